// Round 2
// 311.987 us; speedup vs baseline: 1.0062x; 1.0062x over previous
//
#include <hip/hip_runtime.h>

// NCE loss: N=4096, E=1024, V=50257, K=25, NORM_TERM=9.0
// loss = -sum_n [ log(p0/(p0+25*pn_t)) + sum_k log(25*pn_k/(pk+25*pn_k)) ] / N
// p_j = exp(bias[idx] + dot(x[n], W[idx]) - 9).
//
// One 512-thread block (8 waves) per sample. Waves 0,1 own 4 rows, waves 2..7
// own 3 rows (j = wave + 8*jj covers 0..25 exactly). Per wave: two-phase
// (issue all 16-20 dwordx4 loads, then FMA) with only 4 rows live ->
// wr[4][4]=64 VGPRs payload; __launch_bounds__(512,4) targets <=128 VGPR ->
// 4 waves/SIMD (2 blocks/CU), ~2x the round-0 occupancy.
// bias/noise prefetched as wave-uniform scalar loads so the epilogue is pure
// ALU. Workspace contract: 256 floats (1 KB) ONLY — block partial goes through
// one atomicAdd into 256 spread buckets (16 adds/bucket), as in the verified
// round-0 kernel. (Round-1 wrote 16 KB to d_ws without checking ws_size ->
// heap corruption -> container crash.)

#define NN 4096
#define EE 1024
#define KK 25
#define NBUCKET 256

__device__ __forceinline__ void fma4(float4& a, const float4& p, const float4& q) {
    a.x += p.x * q.x; a.y += p.y * q.y; a.z += p.z * q.z; a.w += p.w * q.w;
}

__global__ __launch_bounds__(512, 4) void nce_main_kernel(
    const float* __restrict__ x,
    const int* __restrict__ target,
    const int* __restrict__ noise_idx,
    const float* __restrict__ weight,
    const float* __restrict__ bias,
    const float* __restrict__ noise,
    float* __restrict__ buckets)
{
    const int n = blockIdx.x;
    const int wave = threadIdx.x >> 6;   // 0..7
    const int lane = threadIdx.x & 63;
    const int nj = (wave < 2) ? 4 : 3;   // rows per wave: 4,4,3,3,3,3,3,3 = 26

    // ---- phase 0: wave-uniform index loads (scalar), bias/noise prefetch ----
    int rows[4];
#pragma unroll
    for (int jj = 0; jj < 4; ++jj) {
        const int j = wave + (jj << 3);  // 0..25 for active jj
        rows[jj] = (jj < nj) ? ((j == 0) ? target[n] : noise_idx[n * KK + (j - 1)])
                             : 0;
    }
    float bv[4], nv[4];
#pragma unroll
    for (int jj = 0; jj < 4; ++jj) {
        bv[jj] = bias[rows[jj]];   // wave-uniform -> scalar loads, overlap with
        nv[jj] = noise[rows[jj]];  // the weight vector loads below
    }

    // ---- phase 1: issue ALL vector loads (4 x + 12/16 weight dwordx4) ----
    const float4* x4 = (const float4*)(x + (size_t)n * EE);
    float4 xr[4];
#pragma unroll
    for (int p = 0; p < 4; ++p) xr[p] = x4[(p << 6) + lane];

    float4 wr[4][4];
#pragma unroll
    for (int jj = 0; jj < 3; ++jj) {
        const float4* w4 = (const float4*)(weight + (size_t)rows[jj] * EE);
#pragma unroll
        for (int p = 0; p < 4; ++p) wr[jj][p] = w4[(p << 6) + lane];
    }
    if (nj == 4) {  // wave-uniform branch, waves 0,1 only
        const float4* w4 = (const float4*)(weight + (size_t)rows[3] * EE);
#pragma unroll
        for (int p = 0; p < 4; ++p) wr[3][p] = w4[(p << 6) + lane];
    }

    // ---- phase 2: FMAs ----
    float sacc[4];
#pragma unroll
    for (int jj = 0; jj < 3; ++jj) {
        float4 a = make_float4(0.f, 0.f, 0.f, 0.f);
#pragma unroll
        for (int p = 0; p < 4; ++p) fma4(a, xr[p], wr[jj][p]);
        sacc[jj] = (a.x + a.y) + (a.z + a.w);
    }
    sacc[3] = 0.f;
    if (nj == 4) {
        float4 a = make_float4(0.f, 0.f, 0.f, 0.f);
#pragma unroll
        for (int p = 0; p < 4; ++p) fma4(a, xr[p], wr[3][p]);
        sacc[3] = (a.x + a.y) + (a.z + a.w);
    }

    // ---- phase 3: butterfly reductions (3 or 4 independent chains) ----
#pragma unroll
    for (int jj = 0; jj < 3; ++jj) {
#pragma unroll
        for (int off = 32; off > 0; off >>= 1)
            sacc[jj] += __shfl_xor(sacc[jj], off);
    }
    if (nj == 4) {
#pragma unroll
        for (int off = 32; off > 0; off >>= 1)
            sacc[3] += __shfl_xor(sacc[3], off);
    }

    // ---- phase 4: per-wave epilogue (pure ALU), block reduce, one atomic ----
    __shared__ float wpart[8];
    if (lane == 0) {
        float part = 0.0f;
#pragma unroll
        for (int jj = 0; jj < 4; ++jj) {
            if (jj < nj) {
                const float logit = sacc[jj] + bv[jj];
                const float p = expf(logit - 9.0f);
                const float pn25 = 25.0f * nv[jj];
                part += (wave == 0 && jj == 0) ? logf(p / (p + pn25))
                                               : logf(pn25 / (p + pn25));
            }
        }
        wpart[wave] = part;
    }
    __syncthreads();
    if (threadIdx.x == 0) {
        float t = 0.f;
#pragma unroll
        for (int w = 0; w < 8; ++w) t += wpart[w];
        atomicAdd(&buckets[n & (NBUCKET - 1)], -t);
    }
}

__global__ __launch_bounds__(64) void nce_finalize_kernel(
    const float* __restrict__ buckets, float* __restrict__ out)
{
    float acc = buckets[threadIdx.x] + buckets[threadIdx.x + 64]
              + buckets[threadIdx.x + 128] + buckets[threadIdx.x + 192];
#pragma unroll
    for (int off = 32; off > 0; off >>= 1)
        acc += __shfl_xor(acc, off);
    if (threadIdx.x == 0)
        out[0] = acc / (float)NN;
}

extern "C" void kernel_launch(void* const* d_in, const int* in_sizes, int n_in,
                              void* d_out, int out_size, void* d_ws, size_t ws_size,
                              hipStream_t stream) {
    const float* x        = (const float*)d_in[0];
    const int*   target   = (const int*)d_in[1];
    const int*   noiseIdx = (const int*)d_in[2];
    const float* weight   = (const float*)d_in[3];
    const float* bias     = (const float*)d_in[4];
    const float* noise    = (const float*)d_in[5];
    float* out = (float*)d_out;
    float* buckets = (float*)d_ws;  // NBUCKET floats = 1 KB, verified footprint

    hipMemsetAsync(buckets, 0, NBUCKET * sizeof(float), stream);
    nce_main_kernel<<<NN, 512, 0, stream>>>(x, target, noiseIdx, weight, bias, noise, buckets);
    nce_finalize_kernel<<<1, 64, 0, stream>>>(buckets, out);
}